// Round 1
// baseline (675.541 us; speedup 1.0000x reference)
//
#include <hip/hip_runtime.h>

// FactorizedQuantizedDistribution:
//   params [B, 255, H, W] f32 tree-node logits, sample [B, H, W] f32 in [0,1)
//   out[b] = sum_{h,w} sum_{x=0..7} v*logit - softplus(logit) along the tree path.
//
// R2: STREAM, don't gather. The gather version (612 us) is random-64B-line
// bound (~0.4 TB/s effective): at levels x>=4 the 2^x candidate rows make each
// wave-load hit ~16 distinct lines per 16-pixel group. Instead every thread
// reads ALL 255 rows at its own pixel column (float4, fully coalesced,
// sequential over rows = 535 MB at streaming BW ~= 90 us) and selects the 8
// path values with cmp+cndmask. Node range split into 4 chunks over
// blockIdx.z for occupancy; chunk boundaries align with tree levels.

#define NB 8       // num_bits
#define NCHUNK 4
#define PIXPT 4    // pixels per thread (one float4)

__global__ __launch_bounds__(256, 4) void fqd_stream(
    const float* __restrict__ params,   // [B, 255, P]
    const float* __restrict__ sample,   // [B, P]
    float* __restrict__ out,            // [B]
    int P)
{
    const int b = blockIdx.y;
    const int c = blockIdx.z;
    const int pix0 = (blockIdx.x * blockDim.x + threadIdx.x) * PIXPT;

    // Contiguous node range [n0, n1) for this chunk.
    // c=0: [0,63)=levels 0..5, c=1: [63,127)=level 6, c=2/3: level 7 halves.
    const int n0 = (255 * c) / NCHUNK;
    const int n1 = (255 * (c + 1)) / NCHUNK;

    const float4 s4 = *reinterpret_cast<const float4*>(sample + (size_t)b * P + pix0);
    int sv[PIXPT];
    sv[0] = (int)(s4.x * 256.0f) & 255;
    sv[1] = (int)(s4.y * 256.0f) & 255;
    sv[2] = (int)(s4.z * 256.0f) & 255;
    sv[3] = (int)(s4.w * 256.0f) & 255;

    const float* pb = params + (size_t)b * 255 * (size_t)P + pix0;

    float sum = 0.0f;

#pragma unroll
    for (int x = 0; x < NB; ++x) {
        const int base = (1 << x) - 1;
        const int jlo = max(0, n0 - base);
        const int jhi = min(1 << x, n1 - base);
        if (jlo >= jhi) continue;            // uniform per block (depends on c only)

        // prefix of x MSBs = the j this pixel needs at level x
        int pref[PIXPT];
#pragma unroll
        for (int p = 0; p < PIXPT; ++p) pref[p] = sv[p] >> (NB - x);

        float cur[PIXPT] = {0.0f, 0.0f, 0.0f, 0.0f};
        const float* rp = pb + (size_t)(base + jlo) * P;
#pragma unroll 4
        for (int j = jlo; j < jhi; ++j) {
            const float4 v = *reinterpret_cast<const float4*>(rp);
            rp += P;
            cur[0] = (j == pref[0]) ? v.x : cur[0];
            cur[1] = (j == pref[1]) ? v.y : cur[1];
            cur[2] = (j == pref[2]) ? v.z : cur[2];
            cur[3] = (j == pref[3]) ? v.w : cur[3];
        }

        // Epilogue: this level contributes iff its matching j fell in our range.
#pragma unroll
        for (int p = 0; p < PIXPT; ++p) {
            if (pref[p] >= jlo && pref[p] < jhi) {
                const float l = cur[p];
                const int bit = (sv[p] >> (NB - 1 - x)) & 1;
                // v*l - softplus(l) = (bit ? min(l,0) : -max(l,0)) - log1p(exp(-|l|))
                const float lin = bit ? fminf(l, 0.0f) : -fmaxf(l, 0.0f);
                sum += lin - log1pf(__expf(-fabsf(l)));
            }
        }
    }

    // Wave (64-lane) shuffle reduction, LDS across 4 waves, one atomic per block.
#pragma unroll
    for (int off = 32; off > 0; off >>= 1)
        sum += __shfl_down(sum, off, 64);

    __shared__ float red[4];
    const int lane = threadIdx.x & 63;
    const int wid  = threadIdx.x >> 6;
    if (lane == 0) red[wid] = sum;
    __syncthreads();
    if (threadIdx.x == 0) {
        atomicAdd(out + b, red[0] + red[1] + red[2] + red[3]);
    }
}

extern "C" void kernel_launch(void* const* d_in, const int* in_sizes, int n_in,
                              void* d_out, int out_size, void* d_ws, size_t ws_size,
                              hipStream_t stream) {
    const float* params = (const float*)d_in[0];
    const float* sample = (const float*)d_in[1];
    float* out = (float*)d_out;

    const int B = out_size;                    // 8
    const int P = in_sizes[1] / B;             // 65536 pixels per batch

    // d_out is poisoned before every call; zero it for the atomics.
    hipMemsetAsync(d_out, 0, (size_t)out_size * sizeof(float), stream);

    const int threads = 256;
    dim3 grid(P / (threads * PIXPT), B, NCHUNK);   // (64, 8, 4) = 2048 blocks
    fqd_stream<<<grid, threads, 0, stream>>>(params, sample, out, P);
}